// Round 19
// baseline (131.220 us; speedup 1.0000x reference)
//
#include <hip/hip_runtime.h>
#include <hip/hip_bf16.h>

typedef __attribute__((ext_vector_type(8))) __bf16 bf16x8;
typedef __attribute__((ext_vector_type(4))) float f32x4;

__device__ __forceinline__ unsigned pk2bf(float lo, float hi) {
  __hip_bfloat162 h = __float22bfloat162_rn(make_float2(lo, hi));
  unsigned u;
  __builtin_memcpy(&u, &h, 4);
  return u;
}

__device__ __forceinline__ void gload_lds16(const void* g, void* l) {
  __builtin_amdgcn_global_load_lds(
      (const __attribute__((address_space(1))) unsigned int*)g,
      (__attribute__((address_space(3))) unsigned int*)l, 16, 0, 0);
}

// ---------------- K1: pooling partials + x -> bf16 in [b][g][y][x][32ch] ----------------
__global__ __launch_bounds__(256) void k_pool_convert(
    const float* __restrict__ x, float* __restrict__ psum,
    unsigned short* __restrict__ xbf) {
  __shared__ float xs[128][65];
  const int b = blockIdx.x >> 6;
  const int y = blockIdx.x & 63;
  const int t = threadIdx.x;
  const float* src = x + ((size_t)b * 128) * 4096 + y * 64;
#pragma unroll
  for (int i = 0; i < 8; ++i) {
    int idx = t + i * 256;
    int c = idx >> 4, x4 = (idx & 15) << 2;
    float4 v = *(const float4*)(src + (size_t)c * 4096 + x4);
    xs[c][x4] = v.x; xs[c][x4 + 1] = v.y; xs[c][x4 + 2] = v.z; xs[c][x4 + 3] = v.w;
  }
  __syncthreads();
  if (t < 128) {
    float s = 0.f;
#pragma unroll
    for (int j = 0; j < 64; ++j) s += xs[t][j];
    psum[((size_t)b * 128 + t) * 64 + y] = s;
  }
#pragma unroll
  for (int i = 0; i < 4; ++i) {
    int idx = t + i * 256;                 // [g(4)][x(64)][q(4)]
    int q = idx & 3, xx = (idx >> 2) & 63, g = idx >> 8;
    unsigned wd[4];
#pragma unroll
    for (int j = 0; j < 4; ++j)
      wd[j] = pk2bf(xs[g * 32 + q * 8 + 2 * j][xx], xs[g * 32 + q * 8 + 2 * j + 1][xx]);
    *(uint4*)(xbf + ((((size_t)b * 4 + g) * 4096) + y * 64 + xx) * 32 + q * 8) =
        make_uint4(wd[0], wd[1], wd[2], wd[3]);
  }
}

// ---------------- K2: routing (fp32 exact), 512 threads, float4 dots ----------------
__global__ __launch_bounds__(512) void k_route(
    const float* __restrict__ psum, const float* __restrict__ w_fc1,
    const float* __restrict__ g1, const float* __restrict__ be1,
    const float* __restrict__ m1, const float* __restrict__ v1,
    const float* __restrict__ w_fc2, const float* __restrict__ bfc2,
    const float* __restrict__ g2, const float* __restrict__ be2,
    const float* __restrict__ m2, const float* __restrict__ v2,
    const float* __restrict__ ab, float* __restrict__ theta,
    float* __restrict__ bias) {
  __shared__ float pooled[128], hs[128], r8[8], tkm[4];
  const int b = blockIdx.x, t = threadIdx.x;
  const int wv = t >> 6;
  if (t < 128) {
    const float4* ps = (const float4*)(psum + ((size_t)b * 128 + t) * 64);
    float sx = 0.f, sy = 0.f, sz = 0.f, sw = 0.f;
#pragma unroll
    for (int j = 0; j < 16; ++j) { float4 v = ps[j]; sx += v.x; sy += v.y; sz += v.z; sw += v.w; }
    pooled[t] = (sx + sy + sz + sw) * (1.0f / 4096.0f);
  }
  __syncthreads();
  if (t < 128) {
    const float4* w1 = (const float4*)(w_fc1 + t * 128);
    const float4* pp = (const float4*)pooled;
    float acc = 0.f;
#pragma unroll
    for (int i = 0; i < 32; ++i) {
      float4 w = w1[i], p = pp[i];
      acc += w.x * p.x + w.y * p.y + w.z * p.z + w.w * p.w;
    }
    acc = (acc - m1[t]) * g1[t] * rsqrtf(v1[t] + 1e-5f) + be1[t];
    hs[t] = fmaxf(acc, 0.f);
  }
  __syncthreads();
  const float4* w2 = (const float4*)(w_fc2 + (size_t)t * 128);
  const float4* hv = (const float4*)hs;
  float a2 = bfc2[t];
#pragma unroll
  for (int i = 0; i < 32; ++i) {
    float4 w = w2[i], h = hv[i];
    a2 += w.x * h.x + w.y * h.y + w.z * h.z + w.w * h.w;
  }
  a2 = (a2 - m2[t]) * g2[t] * rsqrtf(v2[t] + 1e-5f) + be2[t];
  float tv = a2 * (1.0f / 34.0f);
  float mx = tv;
  for (int o = 32; o; o >>= 1) mx = fmaxf(mx, __shfl_xor(mx, o));
  if ((t & 63) == 0) r8[wv] = mx;
  __syncthreads();
  mx = fmaxf(fmaxf(fmaxf(r8[0], r8[1]), fmaxf(r8[2], r8[3])),
             fmaxf(fmaxf(r8[4], r8[5]), fmaxf(r8[6], r8[7])));
  float e = expf(tv - mx);
  float ss = e;
  for (int o = 32; o; o >>= 1) ss += __shfl_xor(ss, o);
  __syncthreads();
  if ((t & 63) == 0) r8[wv] = ss;
  __syncthreads();
  float tot = (r8[0] + r8[1]) + (r8[2] + r8[3]) + (r8[4] + r8[5]) + (r8[6] + r8[7]);
  float th = e / tot;
  theta[b * 512 + t] = th;
  float pv = th;
  for (int o = 32; o; o >>= 1) pv += __shfl_xor(pv, o);
  __syncthreads();
  if ((t & 63) == 0) r8[wv] = pv;
  __syncthreads();
  if (t < 4) tkm[t] = (r8[2 * t] + r8[2 * t + 1]) * (1.0f / 128.0f);
  __syncthreads();
  if (t < 256) {
    float bb = 0.f;
#pragma unroll
    for (int k = 0; k < 4; ++k) bb += tkm[k] * ab[k * 256 + t];
    bias[b * 256 + t] = bb;
  }
}

// ---------------- K3: weight mixing -> bf16 [b][ks][2 obl][128o][32i] halves, pre-swizzled ----------------
__global__ __launch_bounds__(256) void k_mix(
    const float* __restrict__ aw, const float* __restrict__ theta,
    unsigned short* __restrict__ wmix) {
  __shared__ float aw_s[4][32][33];   // [k][i32][o32]
  __shared__ float th_s[32][4][32];   // [b][k][i32]
  const int bx = blockIdx.x;
  const int oq = bx & 3, obl = (bx >> 2) & 1, ks = bx >> 3;
  const int g = ks / 9, tt = ks % 9;
  const int tid = threadIdx.x;
#pragma unroll
  for (int i = 0; i < 16; ++i) {
    int e = tid + i * 256;
    int i32 = e & 31, o32 = (e >> 5) & 31, k = e >> 10;
    aw_s[k][i32][o32] =
        aw[((size_t)((k * 256 + obl * 128 + oq * 32 + o32) * 128) + g * 32 + i32) * 9 + tt];
    int kb = (e >> 5) & 3, bb = e >> 7;
    th_s[bb][kb][i32] = theta[bb * 512 + kb * 128 + g * 32 + i32];
  }
  __syncthreads();
  for (int it = 0; it < 16; ++it) {
    int b = it * 2 + (tid >> 7);
    int u = tid & 127;
    int o32 = u >> 2, q = u & 3;
    unsigned wd[4];
#pragma unroll
    for (int jj = 0; jj < 4; ++jj) {
      int i0 = q * 8 + jj * 2, i1 = i0 + 1;
      float v0 = th_s[b][0][i0] * aw_s[0][i0][o32] + th_s[b][1][i0] * aw_s[1][i0][o32]
               + th_s[b][2][i0] * aw_s[2][i0][o32] + th_s[b][3][i0] * aw_s[3][i0][o32];
      float v1 = th_s[b][0][i1] * aw_s[0][i1][o32] + th_s[b][1][i1] * aw_s[1][i1][o32]
               + th_s[b][2][i1] * aw_s[2][i1][o32] + th_s[b][3][i1] * aw_s[3][i1][o32];
      wd[jj] = pk2bf(v0, v1);
    }
    unsigned A = (unsigned)(((oq * 32 + o32) * 32 + q * 8) * 2);
    unsigned P = A ^ ((A >> 2) & 0x70u);
    size_t tilebase = (((size_t)b * 36 + ks) * 2 + obl) * 8192;
    *(uint4*)((char*)wmix + tilebase + P) = make_uint4(wd[0], wd[1], wd[2], wd[3]);
  }
}

// ---------------- K4: per-sample conv, 256o x 128p block, R4 schedule (no setprio: T5 null on lockstep) ----------------
__global__ __launch_bounds__(256, 2) void k_conv(
    const unsigned short* __restrict__ xbf, const unsigned short* __restrict__ wmix,
    const float* __restrict__ bias, float* __restrict__ out) {
  __shared__ __align__(16) char xls[21120];      // [4 rows][66 cols][pitch 80B]
  __shared__ __align__(16) char wls[2][16384];   // dbuf W tile [256o][32i] (swizzled)
  const int bx = blockIdx.x;
  // T1: bijective XCD swizzle (1024 % 8 == 0): each XCD owns 4 consecutive b's
  const int wgid = ((bx & 7) << 7) | (bx >> 3);
  const int b = wgid >> 5, pblk = wgid & 31;
  const int tid = threadIdx.x;
  const int lane = tid & 63, wv = tid >> 6;      // wave wv owns o in [wv*64, wv*64+64)
  const int y0 = pblk << 1;
  const int l15 = lane & 15, l4 = lane >> 4;

  unsigned a_off0 = ((unsigned)(l15 * 64 + l4 * 16)) ^ ((unsigned)(l15 & 7) << 4);
  a_off0 += (unsigned)(wv * 4096);

  f32x4 acc[4][8] = {};

  const unsigned short* xsrc_b = xbf + (size_t)b * 4 * 4096 * 32;

  auto stageW = [&](int ks, int buf) {
    const char* wsrc = (const char*)wmix + (size_t)(b * 36 + ks) * 16384;
#pragma unroll
    for (int p = 0; p < 4; ++p)
      gload_lds16(wsrc + p * 4096 + wv * 1024 + lane * 16,
                  wls[buf] + p * 4096 + wv * 1024);
  };

  uint4 xr[5];
  auto loadX = [&](int g) {
    const unsigned short* xsrc = xsrc_b + (size_t)g * (4096 * 32);
#pragma unroll
    for (int i = 0; i < 4; ++i) {
      int e = tid + i * 256;
      int q = e & 3, rc = e >> 2, c = rc % 66, r = rc / 66;
      int yy = y0 - 1 + r, xx = c - 1;
      uint4 v = make_uint4(0u, 0u, 0u, 0u);
      if ((unsigned)yy < 64u && (unsigned)xx < 64u)
        v = *(const uint4*)(xsrc + (((size_t)yy << 6) + xx) * 32 + q * 8);
      xr[i] = v;
    }
    if (tid < 32) {
      int e = tid + 1024;
      int q = e & 3, rc = e >> 2, c = rc % 66, r = rc / 66;
      int yy = y0 - 1 + r, xx = c - 1;
      uint4 v = make_uint4(0u, 0u, 0u, 0u);
      if ((unsigned)yy < 64u && (unsigned)xx < 64u)
        v = *(const uint4*)(xsrc + (((size_t)yy << 6) + xx) * 32 + q * 8);
      xr[4] = v;
    }
  };
  auto writeX = [&]() {
#pragma unroll
    for (int i = 0; i < 4; ++i) {
      int e = tid + i * 256;
      int q = e & 3, rc = e >> 2, c = rc % 66, r = rc / 66;
      *(uint4*)(xls + (r * 66 + c) * 80 + q * 16) = xr[i];
    }
    if (tid < 32) {
      int e = tid + 1024;
      int q = e & 3, rc = e >> 2, c = rc % 66, r = rc / 66;
      *(uint4*)(xls + (r * 66 + c) * 80 + q * 16) = xr[4];
    }
  };

  // ---- prologue: stage x halo for group 0; issue W stage for ks=0 ----
  loadX(0);
  writeX();
  stageW(0, 0);
  asm volatile("s_waitcnt lgkmcnt(0)" ::: "memory");

#pragma unroll
  for (int ks = 0; ks < 36; ++ks) {
    // A: drain stage(ks) (issued one tap ago — a full tap of compute to cover it)
    asm volatile("s_waitcnt vmcnt(0)" ::: "memory");
    __builtin_amdgcn_s_barrier();
    asm volatile("" ::: "memory");
    // B: group boundary — commit prefetched x halo to LDS
    if (ks > 0 && ks % 9 == 0) {
      writeX();
      asm volatile("s_waitcnt lgkmcnt(0)" ::: "memory");
      __builtin_amdgcn_s_barrier();
      asm volatile("" ::: "memory");
    }
    // C: at tap 8, issue next group's x halo loads (drained at next tap's vmcnt(0))
    if (ks % 9 == 8 && ks < 35) {
      loadX(ks / 9 + 1);
      asm volatile("" ::: "memory");
    }
    // D: issue W stage for tap ks+1 into the buffer consumed at tap ks-1
    if (ks + 1 < 36) stageW(ks + 1, (ks + 1) & 1);
    // E: fragments
    const int dy = (ks % 9) / 3, dx = (ks % 9) % 3;
    bf16x8 bfr[8], afr[4];
    const char* bbase = xls + ((0 + dy) * 66 + dx + l15) * 80 + l4 * 16;
#pragma unroll
    for (int pf = 0; pf < 4; ++pf) bfr[pf] = *(const bf16x8*)(bbase + pf * 1280);
#pragma unroll
    for (int pf = 0; pf < 4; ++pf) bfr[pf + 4] = *(const bf16x8*)(bbase + 5280 + pf * 1280);
    const char* abase = wls[ks & 1] + a_off0;
#pragma unroll
    for (int of = 0; of < 4; ++of) afr[of] = *(const bf16x8*)(abase + of * 1024);
    // F: MFMA cluster (no setprio — T5 is null/negative on lockstep schedules, m190)
#pragma unroll
    for (int of = 0; of < 4; ++of)
#pragma unroll
      for (int pf = 0; pf < 8; ++pf)
        acc[of][pf] = __builtin_amdgcn_mfma_f32_16x16x32_bf16(afr[of], bfr[pf], acc[of][pf], 0, 0, 0);
  }

  // epilogue: bias + store (fp32)
  const float* bp = bias + b * 256 + wv * 64;
  float bv[4][4];
#pragma unroll
  for (int of = 0; of < 4; ++of)
#pragma unroll
    for (int j = 0; j < 4; ++j) bv[of][j] = bp[of * 16 + l4 * 4 + j];
  size_t outbase = ((size_t)(b * 256 + wv * 64)) * 4096 + (size_t)y0 * 64;
#pragma unroll
  for (int of = 0; of < 4; ++of)
#pragma unroll
    for (int pf = 0; pf < 8; ++pf) {
      int py = pf >> 2, px0 = (pf & 3) * 16;
#pragma unroll
      for (int j = 0; j < 4; ++j)
        out[outbase + (size_t)(of * 16 + l4 * 4 + j) * 4096 + py * 64 + px0 + l15] =
            acc[of][pf][j] + bv[of][j];
    }
}

extern "C" void kernel_launch(void* const* d_in, const int* in_sizes, int n_in,
                              void* d_out, int out_size, void* d_ws, size_t ws_size,
                              hipStream_t stream) {
  const float* x     = (const float*)d_in[0];
  const float* w_fc1 = (const float*)d_in[1];
  const float* g1    = (const float*)d_in[2];
  const float* be1   = (const float*)d_in[3];
  const float* m1    = (const float*)d_in[4];
  const float* v1    = (const float*)d_in[5];
  const float* w_fc2 = (const float*)d_in[6];
  const float* bfc2  = (const float*)d_in[7];
  const float* g2    = (const float*)d_in[8];
  const float* be2   = (const float*)d_in[9];
  const float* m2    = (const float*)d_in[10];
  const float* v2    = (const float*)d_in[11];
  const float* aw    = (const float*)d_in[12];
  const float* ab    = (const float*)d_in[13];
  float* out = (float*)d_out;

  char* ws = (char*)d_ws;
  unsigned short* xbf  = (unsigned short*)(ws);                // 33,554,432 B
  unsigned short* wmix = (unsigned short*)(ws + 33554432);     // 18,874,368 B
  float* psum  = (float*)(ws + 52428800);                      // 1,048,576 B
  float* theta = (float*)(ws + 53477376);                      //    65,536 B
  float* bias  = (float*)(ws + 53542912);                      //    32,768 B

  hipLaunchKernelGGL(k_pool_convert, dim3(2048), dim3(256), 0, stream, x, psum, xbf);
  hipLaunchKernelGGL(k_route, dim3(32), dim3(512), 0, stream, psum, w_fc1, g1, be1, m1, v1,
                     w_fc2, bfc2, g2, be2, m2, v2, ab, theta, bias);
  hipLaunchKernelGGL(k_mix, dim3(288), dim3(256), 0, stream, aw, theta, wmix);
  hipLaunchKernelGGL(k_conv, dim3(1024), dim3(256), 0, stream, xbf, wmix, bias, out);
}

// Round 20
// 123.659 us; speedup vs baseline: 1.0611x; 1.0611x over previous
//
#include <hip/hip_runtime.h>
#include <hip/hip_bf16.h>

typedef __attribute__((ext_vector_type(8))) __bf16 bf16x8;
typedef __attribute__((ext_vector_type(4))) float f32x4;

__device__ __forceinline__ unsigned pk2bf(float lo, float hi) {
  __hip_bfloat162 h = __float22bfloat162_rn(make_float2(lo, hi));
  unsigned u;
  __builtin_memcpy(&u, &h, 4);
  return u;
}

__device__ __forceinline__ void gload_lds16(const void* g, void* l) {
  __builtin_amdgcn_global_load_lds(
      (const __attribute__((address_space(1))) unsigned int*)g,
      (__attribute__((address_space(3))) unsigned int*)l, 16, 0, 0);
}

// ---------------- K1: pooling partials + x -> bf16 in [b][g][y][x][32ch] ----------------
__global__ __launch_bounds__(256) void k_pool_convert(
    const float* __restrict__ x, float* __restrict__ psum,
    unsigned short* __restrict__ xbf) {
  __shared__ float xs[128][65];
  const int b = blockIdx.x >> 6;
  const int y = blockIdx.x & 63;
  const int t = threadIdx.x;
  const float* src = x + ((size_t)b * 128) * 4096 + y * 64;
#pragma unroll
  for (int i = 0; i < 8; ++i) {
    int idx = t + i * 256;
    int c = idx >> 4, x4 = (idx & 15) << 2;
    float4 v = *(const float4*)(src + (size_t)c * 4096 + x4);
    xs[c][x4] = v.x; xs[c][x4 + 1] = v.y; xs[c][x4 + 2] = v.z; xs[c][x4 + 3] = v.w;
  }
  __syncthreads();
  if (t < 128) {
    float s = 0.f;
#pragma unroll
    for (int j = 0; j < 64; ++j) s += xs[t][j];
    psum[((size_t)b * 128 + t) * 64 + y] = s;
  }
#pragma unroll
  for (int i = 0; i < 4; ++i) {
    int idx = t + i * 256;                 // [g(4)][x(64)][q(4)]
    int q = idx & 3, xx = (idx >> 2) & 63, g = idx >> 8;
    unsigned wd[4];
#pragma unroll
    for (int j = 0; j < 4; ++j)
      wd[j] = pk2bf(xs[g * 32 + q * 8 + 2 * j][xx], xs[g * 32 + q * 8 + 2 * j + 1][xx]);
    *(uint4*)(xbf + ((((size_t)b * 4 + g) * 4096) + y * 64 + xx) * 32 + q * 8) =
        make_uint4(wd[0], wd[1], wd[2], wd[3]);
  }
}

// ---------------- K2: routing (fp32 exact), 512 threads, float4 dots ----------------
__global__ __launch_bounds__(512) void k_route(
    const float* __restrict__ psum, const float* __restrict__ w_fc1,
    const float* __restrict__ g1, const float* __restrict__ be1,
    const float* __restrict__ m1, const float* __restrict__ v1,
    const float* __restrict__ w_fc2, const float* __restrict__ bfc2,
    const float* __restrict__ g2, const float* __restrict__ be2,
    const float* __restrict__ m2, const float* __restrict__ v2,
    const float* __restrict__ ab, float* __restrict__ theta,
    float* __restrict__ bias) {
  __shared__ float pooled[128], hs[128], r8[8], tkm[4];
  const int b = blockIdx.x, t = threadIdx.x;
  const int wv = t >> 6;
  if (t < 128) {
    const float4* ps = (const float4*)(psum + ((size_t)b * 128 + t) * 64);
    float sx = 0.f, sy = 0.f, sz = 0.f, sw = 0.f;
#pragma unroll
    for (int j = 0; j < 16; ++j) { float4 v = ps[j]; sx += v.x; sy += v.y; sz += v.z; sw += v.w; }
    pooled[t] = (sx + sy + sz + sw) * (1.0f / 4096.0f);
  }
  __syncthreads();
  if (t < 128) {
    const float4* w1 = (const float4*)(w_fc1 + t * 128);
    const float4* pp = (const float4*)pooled;
    float acc = 0.f;
#pragma unroll
    for (int i = 0; i < 32; ++i) {
      float4 w = w1[i], p = pp[i];
      acc += w.x * p.x + w.y * p.y + w.z * p.z + w.w * p.w;
    }
    acc = (acc - m1[t]) * g1[t] * rsqrtf(v1[t] + 1e-5f) + be1[t];
    hs[t] = fmaxf(acc, 0.f);
  }
  __syncthreads();
  const float4* w2 = (const float4*)(w_fc2 + (size_t)t * 128);
  const float4* hv = (const float4*)hs;
  float a2 = bfc2[t];
#pragma unroll
  for (int i = 0; i < 32; ++i) {
    float4 w = w2[i], h = hv[i];
    a2 += w.x * h.x + w.y * h.y + w.z * h.z + w.w * h.w;
  }
  a2 = (a2 - m2[t]) * g2[t] * rsqrtf(v2[t] + 1e-5f) + be2[t];
  float tv = a2 * (1.0f / 34.0f);
  float mx = tv;
  for (int o = 32; o; o >>= 1) mx = fmaxf(mx, __shfl_xor(mx, o));
  if ((t & 63) == 0) r8[wv] = mx;
  __syncthreads();
  mx = fmaxf(fmaxf(fmaxf(r8[0], r8[1]), fmaxf(r8[2], r8[3])),
             fmaxf(fmaxf(r8[4], r8[5]), fmaxf(r8[6], r8[7])));
  float e = expf(tv - mx);
  float ss = e;
  for (int o = 32; o; o >>= 1) ss += __shfl_xor(ss, o);
  __syncthreads();
  if ((t & 63) == 0) r8[wv] = ss;
  __syncthreads();
  float tot = (r8[0] + r8[1]) + (r8[2] + r8[3]) + (r8[4] + r8[5]) + (r8[6] + r8[7]);
  float th = e / tot;
  theta[b * 512 + t] = th;
  float pv = th;
  for (int o = 32; o; o >>= 1) pv += __shfl_xor(pv, o);
  __syncthreads();
  if ((t & 63) == 0) r8[wv] = pv;
  __syncthreads();
  if (t < 4) tkm[t] = (r8[2 * t] + r8[2 * t + 1]) * (1.0f / 128.0f);
  __syncthreads();
  if (t < 256) {
    float bb = 0.f;
#pragma unroll
    for (int k = 0; k < 4; ++k) bb += tkm[k] * ab[k * 256 + t];
    bias[b * 256 + t] = bb;
  }
}

// ---------------- K3: weight mixing -> bf16 [b][ks][2 obl][128o][32i] halves, pre-swizzled ----------------
__global__ __launch_bounds__(256) void k_mix(
    const float* __restrict__ aw, const float* __restrict__ theta,
    unsigned short* __restrict__ wmix) {
  __shared__ float aw_s[4][32][33];   // [k][i32][o32]
  __shared__ float th_s[32][4][32];   // [b][k][i32]
  const int bx = blockIdx.x;
  const int oq = bx & 3, obl = (bx >> 2) & 1, ks = bx >> 3;
  const int g = ks / 9, tt = ks % 9;
  const int tid = threadIdx.x;
#pragma unroll
  for (int i = 0; i < 16; ++i) {
    int e = tid + i * 256;
    int i32 = e & 31, o32 = (e >> 5) & 31, k = e >> 10;
    aw_s[k][i32][o32] =
        aw[((size_t)((k * 256 + obl * 128 + oq * 32 + o32) * 128) + g * 32 + i32) * 9 + tt];
    int kb = (e >> 5) & 3, bb = e >> 7;
    th_s[bb][kb][i32] = theta[bb * 512 + kb * 128 + g * 32 + i32];
  }
  __syncthreads();
  for (int it = 0; it < 16; ++it) {
    int b = it * 2 + (tid >> 7);
    int u = tid & 127;
    int o32 = u >> 2, q = u & 3;
    unsigned wd[4];
#pragma unroll
    for (int jj = 0; jj < 4; ++jj) {
      int i0 = q * 8 + jj * 2, i1 = i0 + 1;
      float v0 = th_s[b][0][i0] * aw_s[0][i0][o32] + th_s[b][1][i0] * aw_s[1][i0][o32]
               + th_s[b][2][i0] * aw_s[2][i0][o32] + th_s[b][3][i0] * aw_s[3][i0][o32];
      float v1 = th_s[b][0][i1] * aw_s[0][i1][o32] + th_s[b][1][i1] * aw_s[1][i1][o32]
               + th_s[b][2][i1] * aw_s[2][i1][o32] + th_s[b][3][i1] * aw_s[3][i1][o32];
      wd[jj] = pk2bf(v0, v1);
    }
    unsigned A = (unsigned)(((oq * 32 + o32) * 32 + q * 8) * 2);
    unsigned P = A ^ ((A >> 2) & 0x70u);
    size_t tilebase = (((size_t)b * 36 + ks) * 2 + obl) * 8192;
    *(uint4*)((char*)wmix + tilebase + P) = make_uint4(wd[0], wd[1], wd[2], wd[3]);
  }
}

// ---------------- K4: per-sample conv, 256o x 128p block, R4 schedule + setprio (proven 80.2us) ----------------
__global__ __launch_bounds__(256, 2) void k_conv(
    const unsigned short* __restrict__ xbf, const unsigned short* __restrict__ wmix,
    const float* __restrict__ bias, float* __restrict__ out) {
  __shared__ __align__(16) char xls[21120];      // [4 rows][66 cols][pitch 80B]
  __shared__ __align__(16) char wls[2][16384];   // dbuf W tile [256o][32i] (swizzled)
  const int bx = blockIdx.x;
  // T1: bijective XCD swizzle (1024 % 8 == 0): each XCD owns 4 consecutive b's
  const int wgid = ((bx & 7) << 7) | (bx >> 3);
  const int b = wgid >> 5, pblk = wgid & 31;
  const int tid = threadIdx.x;
  const int lane = tid & 63, wv = tid >> 6;      // wave wv owns o in [wv*64, wv*64+64)
  const int y0 = pblk << 1;
  const int l15 = lane & 15, l4 = lane >> 4;

  unsigned a_off0 = ((unsigned)(l15 * 64 + l4 * 16)) ^ ((unsigned)(l15 & 7) << 4);
  a_off0 += (unsigned)(wv * 4096);

  f32x4 acc[4][8] = {};

  const unsigned short* xsrc_b = xbf + (size_t)b * 4 * 4096 * 32;

  auto stageW = [&](int ks, int buf) {
    const char* wsrc = (const char*)wmix + (size_t)(b * 36 + ks) * 16384;
#pragma unroll
    for (int p = 0; p < 4; ++p)
      gload_lds16(wsrc + p * 4096 + wv * 1024 + lane * 16,
                  wls[buf] + p * 4096 + wv * 1024);
  };

  uint4 xr[5];
  auto loadX = [&](int g) {
    const unsigned short* xsrc = xsrc_b + (size_t)g * (4096 * 32);
#pragma unroll
    for (int i = 0; i < 4; ++i) {
      int e = tid + i * 256;
      int q = e & 3, rc = e >> 2, c = rc % 66, r = rc / 66;
      int yy = y0 - 1 + r, xx = c - 1;
      uint4 v = make_uint4(0u, 0u, 0u, 0u);
      if ((unsigned)yy < 64u && (unsigned)xx < 64u)
        v = *(const uint4*)(xsrc + (((size_t)yy << 6) + xx) * 32 + q * 8);
      xr[i] = v;
    }
    if (tid < 32) {
      int e = tid + 1024;
      int q = e & 3, rc = e >> 2, c = rc % 66, r = rc / 66;
      int yy = y0 - 1 + r, xx = c - 1;
      uint4 v = make_uint4(0u, 0u, 0u, 0u);
      if ((unsigned)yy < 64u && (unsigned)xx < 64u)
        v = *(const uint4*)(xsrc + (((size_t)yy << 6) + xx) * 32 + q * 8);
      xr[4] = v;
    }
  };
  auto writeX = [&]() {
#pragma unroll
    for (int i = 0; i < 4; ++i) {
      int e = tid + i * 256;
      int q = e & 3, rc = e >> 2, c = rc % 66, r = rc / 66;
      *(uint4*)(xls + (r * 66 + c) * 80 + q * 16) = xr[i];
    }
    if (tid < 32) {
      int e = tid + 1024;
      int q = e & 3, rc = e >> 2, c = rc % 66, r = rc / 66;
      *(uint4*)(xls + (r * 66 + c) * 80 + q * 16) = xr[4];
    }
  };

  // ---- prologue: stage x halo for group 0; issue W stage for ks=0 ----
  loadX(0);
  writeX();
  stageW(0, 0);
  asm volatile("s_waitcnt lgkmcnt(0)" ::: "memory");

#pragma unroll
  for (int ks = 0; ks < 36; ++ks) {
    // A: drain stage(ks) (issued one tap ago — a full tap of compute to cover it)
    asm volatile("s_waitcnt vmcnt(0)" ::: "memory");
    __builtin_amdgcn_s_barrier();
    asm volatile("" ::: "memory");
    // B: group boundary — commit prefetched x halo to LDS
    if (ks > 0 && ks % 9 == 0) {
      writeX();
      asm volatile("s_waitcnt lgkmcnt(0)" ::: "memory");
      __builtin_amdgcn_s_barrier();
      asm volatile("" ::: "memory");
    }
    // C: at tap 8, issue next group's x halo loads (drained at next tap's vmcnt(0))
    if (ks % 9 == 8 && ks < 35) {
      loadX(ks / 9 + 1);
      asm volatile("" ::: "memory");
    }
    // D: issue W stage for tap ks+1 into the buffer consumed at tap ks-1
    if (ks + 1 < 36) stageW(ks + 1, (ks + 1) & 1);
    // E: fragments
    const int dy = (ks % 9) / 3, dx = (ks % 9) % 3;
    bf16x8 bfr[8], afr[4];
    const char* bbase = xls + ((0 + dy) * 66 + dx + l15) * 80 + l4 * 16;
#pragma unroll
    for (int pf = 0; pf < 4; ++pf) bfr[pf] = *(const bf16x8*)(bbase + pf * 1280);
#pragma unroll
    for (int pf = 0; pf < 4; ++pf) bfr[pf + 4] = *(const bf16x8*)(bbase + 5280 + pf * 1280);
    const char* abase = wls[ks & 1] + a_off0;
#pragma unroll
    for (int of = 0; of < 4; ++of) afr[of] = *(const bf16x8*)(abase + of * 1024);
    // F: MFMA cluster (setprio kept: within-kernel A/B showed −7% without it, R19)
    __builtin_amdgcn_s_setprio(1);
#pragma unroll
    for (int of = 0; of < 4; ++of)
#pragma unroll
      for (int pf = 0; pf < 8; ++pf)
        acc[of][pf] = __builtin_amdgcn_mfma_f32_16x16x32_bf16(afr[of], bfr[pf], acc[of][pf], 0, 0, 0);
    __builtin_amdgcn_s_setprio(0);
  }

  // epilogue: bias + store (fp32)
  const float* bp = bias + b * 256 + wv * 64;
  float bv[4][4];
#pragma unroll
  for (int of = 0; of < 4; ++of)
#pragma unroll
    for (int j = 0; j < 4; ++j) bv[of][j] = bp[of * 16 + l4 * 4 + j];
  size_t outbase = ((size_t)(b * 256 + wv * 64)) * 4096 + (size_t)y0 * 64;
#pragma unroll
  for (int of = 0; of < 4; ++of)
#pragma unroll
    for (int pf = 0; pf < 8; ++pf) {
      int py = pf >> 2, px0 = (pf & 3) * 16;
#pragma unroll
      for (int j = 0; j < 4; ++j)
        out[outbase + (size_t)(of * 16 + l4 * 4 + j) * 4096 + py * 64 + px0 + l15] =
            acc[of][pf][j] + bv[of][j];
    }
}

extern "C" void kernel_launch(void* const* d_in, const int* in_sizes, int n_in,
                              void* d_out, int out_size, void* d_ws, size_t ws_size,
                              hipStream_t stream) {
  const float* x     = (const float*)d_in[0];
  const float* w_fc1 = (const float*)d_in[1];
  const float* g1    = (const float*)d_in[2];
  const float* be1   = (const float*)d_in[3];
  const float* m1    = (const float*)d_in[4];
  const float* v1    = (const float*)d_in[5];
  const float* w_fc2 = (const float*)d_in[6];
  const float* bfc2  = (const float*)d_in[7];
  const float* g2    = (const float*)d_in[8];
  const float* be2   = (const float*)d_in[9];
  const float* m2    = (const float*)d_in[10];
  const float* v2    = (const float*)d_in[11];
  const float* aw    = (const float*)d_in[12];
  const float* ab    = (const float*)d_in[13];
  float* out = (float*)d_out;

  char* ws = (char*)d_ws;
  unsigned short* xbf  = (unsigned short*)(ws);                // 33,554,432 B
  unsigned short* wmix = (unsigned short*)(ws + 33554432);     // 18,874,368 B
  float* psum  = (float*)(ws + 52428800);                      // 1,048,576 B
  float* theta = (float*)(ws + 53477376);                      //    65,536 B
  float* bias  = (float*)(ws + 53542912);                      //    32,768 B

  hipLaunchKernelGGL(k_pool_convert, dim3(2048), dim3(256), 0, stream, x, psum, xbf);
  hipLaunchKernelGGL(k_route, dim3(32), dim3(512), 0, stream, psum, w_fc1, g1, be1, m1, v1,
                     w_fc2, bfc2, g2, be2, m2, v2, ab, theta, bias);
  hipLaunchKernelGGL(k_mix, dim3(288), dim3(256), 0, stream, aw, theta, wmix);
  hipLaunchKernelGGL(k_conv, dim3(1024), dim3(256), 0, stream, xbf, wmix, bias, out);
}